// Round 12
// baseline (116.708 us; speedup 1.0000x reference)
//
#include <hip/hip_runtime.h>
#include <hip/hip_bf16.h>
#include <math.h>

typedef __attribute__((ext_vector_type(8))) _Float16 half8;
typedef __attribute__((ext_vector_type(4))) _Float16 half4;
typedef __attribute__((ext_vector_type(4))) float f32x4;

#define EMBD 128
#define H1 256
#define H2 128
#define SLEN 50
#define NROWS 4096
#define MAXTOK (NROWS * SLEN)          // 204800
#define MTILE 32
#define MAXTILES ((MAXTOK + MTILE - 1) / MTILE)   // 6400
#define DENSE_GRID 1024

// ---- d_ws layout (bytes) ----
//      0 : half8 frags[8192]                (131072)
// 131072 : int counter                      (pad to 131200)
// 131200 : u32 packed[204800]               (819200) -> 950400
// 950400 : float partial[4096][3][128]      (6291456) -> 7241856  (~7.3 MB)
#define WS_FRAGS   0
#define WS_CNT     131072
#define WS_PACKED  131200
#define WS_PARTIAL 950400

// Branch-free GELU, exact-erf form via Abramowitz-Stegun 7.1.26 (|err|<=1.5e-7).
__device__ __forceinline__ float gelu_exact(float h) {
    float ah = fabsf(h);
    float d  = fmaf(0.23163845f, ah, 1.0f);
    float t;
    asm("v_rcp_f32 %0, %1" : "=v"(t) : "v"(d));
    float p = fmaf(1.061405429f, t, -1.453152027f);
    p = fmaf(p, t, 1.421413741f);
    p = fmaf(p, t, -0.284496736f);
    p = fmaf(p, t, 0.254829592f);
    p = p * t;
    float e;                                   // v_exp_f32 computes 2^x
    float x2 = h * h * -0.72134752f;           // -h^2/2 * log2(e)
    asm("v_exp_f32 %0, %1" : "=v"(e) : "v"(x2));
    float er = fmaf(-p, e, 1.0f);
    return fmaf(0.5f * ah, er, 0.5f * h);
}

// LDS-only barrier (no vmcnt drain): in-flight global loads survive it.
#define BARRIER_LDS() asm volatile("s_waitcnt lgkmcnt(0)\n\ts_barrier" ::: "memory")

// ---------------------------------------------------------------------------
// K0: weight fragments (byte-identical layout to R9/R11) + zero counter +
//     init partial sides 1,2 to -inf.  grid 4129 x 256.
// ---------------------------------------------------------------------------
__global__ __launch_bounds__(256) void prep_kernel(
    const float* __restrict__ w1, const float* __restrict__ w2,
    half8* __restrict__ frags, int* __restrict__ cnt,
    float* __restrict__ partial)
{
    int b = blockIdx.x, t = threadIdx.x;
    if (b < 32) {
        int f = b * 256 + t;   // 0..8191
        half8 v;
        if (f < 4096) {
            int lane = f & 63;
            int nt = (f >> 6) & 3, kt = (f >> 8) & 3, w = (f >> 10) & 3;
            int col = w * 64 + nt * 16 + (lane & 15);
            int kb  = kt * 32 + (lane >> 4) * 8;
            #pragma unroll
            for (int i = 0; i < 8; ++i) v[i] = (_Float16)w1[(size_t)(kb + i) * H1 + col];
            frags[f] = v;
        } else {
            int f2 = f - 4096;
            int lane = f2 & 63;
            int nt = (f2 >> 6) & 1, kt = (f2 >> 7) & 7, w = (f2 >> 10) & 3;
            int col = w * 32 + nt * 16 + (lane & 15);
            int kb  = kt * 32 + (lane >> 4) * 8;
            #pragma unroll
            for (int i = 0; i < 8; ++i) v[i] = (_Float16)w2[(size_t)(kb + i) * H2 + col];
            frags[4096 + f2] = v;
        }
    } else if (b == 32) {
        if (t == 0) *cnt = 0;
    } else {
        int idx = (b - 33) * 256 + t;          // 0 .. 4096*256-1
        if (idx < NROWS * 256) {
            int r = idx >> 8, rem = idx & 255;  // rem 0..255 spans sides 1..2
            partial[(size_t)r * 384 + 128 + rem] = -INFINITY;
        }
    }
}

// ---------------------------------------------------------------------------
// K1: compact valid tokens -> packed[i] = emb_id | (row << 17).
//     Wave-level scan + one atomicAdd per wave. grid 16 x 256.
// ---------------------------------------------------------------------------
__global__ __launch_bounds__(256) void compact_kernel(
    const int* __restrict__ ids, const int* __restrict__ lens,
    unsigned* __restrict__ packed, int* __restrict__ cnt)
{
    int gtid = blockIdx.x * 256 + threadIdx.x;   // row 0..4095
    int lane = threadIdx.x & 63;
    int len = lens[gtid]; len = len < 1 ? 1 : (len > SLEN ? SLEN : len);
    int inc = len;
    #pragma unroll
    for (int off = 1; off < 64; off <<= 1) {
        int v = __shfl_up(inc, off, 64);
        if (lane >= off) inc += v;
    }
    int wave_total = __shfl(inc, 63, 64);
    int wbase;
    if (lane == 0) wbase = atomicAdd(cnt, wave_total);
    wbase = __shfl(wbase, 0, 64);
    int base = wbase + inc - len;
    unsigned rtag = (unsigned)gtid << 17;
    for (int t = 0; t < len; ++t)
        packed[base + t] = (unsigned)ids[gtid * SLEN + t] | rtag;
}

// ---------------------------------------------------------------------------
// K2: dense 32-token tiles. Per tile: gather+LN1 -> x_lds -> GEMM1T+GELU ->
//     h1_lds -> GEMM2 -> segment-scan max-pool -> partial[row][span][128].
//     Spans: 0 = segment containing row start; continuations (row crosses a
//     tile boundary, <=2 of them, in CONSECUTIVE tiles) -> 1 + (tile&1).
//     grid DENSE_GRID x 256.
// ---------------------------------------------------------------------------
__global__ __launch_bounds__(256) void dense_kernel(
    const unsigned* __restrict__ packed, const int* __restrict__ cnt,
    const float* __restrict__ emb, const float* __restrict__ ln1g,
    const float* __restrict__ ln1b, const float* __restrict__ b1,
    const float* __restrict__ b2, const half8* __restrict__ wfrag,
    float* __restrict__ partial)
{
    const int tid = threadIdx.x;
    const int w  = tid >> 6;
    const int l  = tid & 63;
    const int ln = l & 15;
    const int lg = l >> 4;
    const int g16 = w * 4 + lg;   // 16-lane group 0..15

    __shared__ __align__(16) _Float16 x_lds[MTILE][EMBD + 8];
    __shared__ __align__(16) _Float16 h1_lds[MTILE][H1 + 8];
    __shared__ unsigned tok_lds[MTILE + 2];

    // ---- weight fragments (same fragment content as R11) ----
    half8 w1f[4][4];
    #pragma unroll
    for (int kt = 0; kt < 4; ++kt)
      #pragma unroll
      for (int nt = 0; nt < 4; ++nt)
        w1f[kt][nt] = wfrag[((w * 4 + kt) * 4 + nt) * 64 + l];
    half8 w2f[8][2];
    #pragma unroll
    for (int kt = 0; kt < 8; ++kt)
      #pragma unroll
      for (int nt = 0; nt < 2; ++nt)
        w2f[kt][nt] = wfrag[4096 + ((w * 8 + kt) * 2 + nt) * 64 + l];

    float g1r[8], b1r[8];
    #pragma unroll
    for (int i = 0; i < 8; ++i) { g1r[i] = ln1g[ln * 8 + i]; b1r[i] = ln1b[ln * 8 + i]; }
    f32x4 b1tv[4];
    #pragma unroll
    for (int nt = 0; nt < 4; ++nt)
        b1tv[nt] = *(const f32x4*)&b1[w * 64 + nt * 16 + lg * 4];
    float b2v[2];
    #pragma unroll
    for (int nt = 0; nt < 2; ++nt) b2v[nt] = b2[w * 32 + nt * 16 + ln];

    const int total = *cnt;

    for (int tile = blockIdx.x; tile * MTILE < total; tile += gridDim.x) {
        const int base = tile * MTILE;

        // ---- stage token tags ----
        if (tid < MTILE) {
            unsigned pk = 0xFFFFFFFFu;
            if (base + tid < total) pk = packed[base + tid];
            tok_lds[tid] = pk;
        } else if (tid == MTILE) {
            tok_lds[MTILE] = (base > 0) ? packed[base - 1] : 0xFFFFFFFFu;
        }

        // ---- gather + LN1 for tokens g16 and g16+16 ----
        #pragma unroll
        for (int s = 0; s < 2; ++s) {
            int tl = s * 16 + g16;
            int gidx = base + tl;
            half8 xo;
            if (gidx < total) {
                unsigned pk = packed[gidx];
                int id = (int)(pk & 0x1FFFFu);
                const float4* src = (const float4*)(emb + (size_t)id * EMBD + ln * 8);
                float4 p0 = src[0], p1 = src[1];
                float v[8] = {p0.x, p0.y, p0.z, p0.w, p1.x, p1.y, p1.z, p1.w};
                float sm = 0.f, ss = 0.f;
                #pragma unroll
                for (int k = 0; k < 8; ++k) { sm += v[k]; ss += v[k] * v[k]; }
                #pragma unroll
                for (int m = 1; m < 16; m <<= 1) {
                    sm += __shfl_xor(sm, m, 64);
                    ss += __shfl_xor(ss, m, 64);
                }
                float mu  = sm * (1.f / 128.f);
                float var = ss * (1.f / 128.f) - mu * mu;
                float rs  = rsqrtf(var + 1e-12f);
                #pragma unroll
                for (int k = 0; k < 8; ++k)
                    xo[k] = (_Float16)((v[k] - mu) * rs * g1r[k] + b1r[k]);
            } else {
                #pragma unroll
                for (int k = 0; k < 8; ++k) xo[k] = (_Float16)0.f;
            }
            *(half8*)&x_lds[tl][ln * 8] = xo;
        }

        BARRIER_LDS();   // x_lds + tok_lds ready

        // ---- GEMM1 (transposed, as R11) + GELU -> h1_lds ----
        f32x4 acc[2][4];
        #pragma unroll
        for (int m = 0; m < 2; ++m)
          #pragma unroll
          for (int nt = 0; nt < 4; ++nt) acc[m][nt] = (f32x4){0,0,0,0};
        #pragma unroll
        for (int kt = 0; kt < 4; ++kt) {
            half8 bf0 = *(const half8*)&x_lds[ln][kt * 32 + lg * 8];
            half8 bf1 = *(const half8*)&x_lds[16 + ln][kt * 32 + lg * 8];
            #pragma unroll
            for (int nt = 0; nt < 4; ++nt) {
                acc[0][nt] = __builtin_amdgcn_mfma_f32_16x16x32_f16(w1f[kt][nt], bf0, acc[0][nt], 0, 0, 0);
                acc[1][nt] = __builtin_amdgcn_mfma_f32_16x16x32_f16(w1f[kt][nt], bf1, acc[1][nt], 0, 0, 0);
            }
        }
        #pragma unroll
        for (int m = 0; m < 2; ++m)
          #pragma unroll
          for (int nt = 0; nt < 4; ++nt) {
            half4 hv;
            #pragma unroll
            for (int g2 = 0; g2 < 4; ++g2) {
                float h = acc[m][nt][g2] + b1tv[nt][g2];
                hv[g2] = (_Float16)gelu_exact(h);
            }
            *(half4*)&h1_lds[m * 16 + ln][w * 64 + nt * 16 + lg * 4] = hv;
          }

        BARRIER_LDS();   // h1_lds ready

        // ---- GEMM2 (standard orientation, as R9/R11) ----
        f32x4 acc2[2][2];
        #pragma unroll
        for (int m = 0; m < 2; ++m) { acc2[m][0] = (f32x4){0,0,0,0}; acc2[m][1] = (f32x4){0,0,0,0}; }
        #pragma unroll
        for (int kt = 0; kt < 8; ++kt) {
            half8 a0 = *(const half8*)&h1_lds[ln][kt * 32 + lg * 8];
            half8 a1 = *(const half8*)&h1_lds[16 + ln][kt * 32 + lg * 8];
            #pragma unroll
            for (int nt = 0; nt < 2; ++nt) {
                acc2[0][nt] = __builtin_amdgcn_mfma_f32_16x16x32_f16(a0, w2f[kt][nt], acc2[0][nt], 0, 0, 0);
                acc2[1][nt] = __builtin_amdgcn_mfma_f32_16x16x32_f16(a1, w2f[kt][nt], acc2[1][nt], 0, 0, 0);
            }
        }
        // value for token tt = m*16+lg*4+g2, cols w*32+ln (v0) and w*32+16+ln (v1)
        float val0[2][4], val1[2][4];
        #pragma unroll
        for (int m = 0; m < 2; ++m)
          #pragma unroll
          for (int g2 = 0; g2 < 4; ++g2) {
            val0[m][g2] = acc2[m][0][g2] + b2v[0];
            val1[m][g2] = acc2[m][1][g2] + b2v[1];
          }

        // ---- segment scan + pool (rows are contiguous runs in the tile) ----
        {
            int prev_row = (int)(tok_lds[MTILE] >> 17);
            int cur_row  = (int)(tok_lds[0] >> 17);
            int s0 = 0;
            bool firstSeg = true;
            for (int j = 1; j <= MTILE; ++j) {
                int rj = (j < MTILE) ? (int)(tok_lds[j] >> 17) : -1;
                if (j == MTILE || rj != cur_row) {
                    if (cur_row < NROWS) {
                        float mx0 = -INFINITY, mx1 = -INFINITY;
                        #pragma unroll
                        for (int m = 0; m < 2; ++m)
                          #pragma unroll
                          for (int g2 = 0; g2 < 4; ++g2) {
                            int tt = m * 16 + lg * 4 + g2;
                            bool in = (tt >= s0) && (tt < j);
                            if (in) { mx0 = fmaxf(mx0, val0[m][g2]); mx1 = fmaxf(mx1, val1[m][g2]); }
                          }
                        mx0 = fmaxf(mx0, __shfl_xor(mx0, 16, 64));
                        mx0 = fmaxf(mx0, __shfl_xor(mx0, 32, 64));
                        mx1 = fmaxf(mx1, __shfl_xor(mx1, 16, 64));
                        mx1 = fmaxf(mx1, __shfl_xor(mx1, 32, 64));
                        int side = 0;
                        if (firstSeg && s0 == 0 && base > 0 && prev_row == cur_row)
                            side = 1 + (tile & 1);
                        if (lg == 0) {
                            float* dst = partial + (size_t)cur_row * 384 + side * 128 + w * 32 + ln;
                            dst[0]  = mx0;
                            dst[16] = mx1;
                        }
                    }
                    firstSeg = false;
                    s0 = j; cur_row = rj;
                }
            }
        }

        BARRIER_LDS();   // protect x_lds/h1_lds/tok_lds for next tile
    }
}

// ---------------------------------------------------------------------------
// K3: pool = max over 3 spans -> LN2 -> fc. One wave per row, grid 1024 x 256.
// ---------------------------------------------------------------------------
__global__ __launch_bounds__(256) void head_kernel(
    const float* __restrict__ partial, const float* __restrict__ ln2g,
    const float* __restrict__ ln2b, const float* __restrict__ fcw,
    const float* __restrict__ fcb, float* __restrict__ out)
{
    int w = threadIdx.x >> 6, l = threadIdx.x & 63;
    int r = blockIdx.x * 4 + w;
    const float* pr = partial + (size_t)r * 384;
    float v0 = fmaxf(fmaxf(pr[l],      pr[128 + l]),      pr[256 + l]);
    float v1 = fmaxf(fmaxf(pr[64 + l], pr[128 + 64 + l]), pr[256 + 64 + l]);
    float g2a = ln2g[l], g2c = ln2g[l + 64];
    float b2a = ln2b[l], b2c = ln2b[l + 64];
    float fwa = fcw[l],  fwc = fcw[l + 64];
    float s = v0 + v1, ss = v0 * v0 + v1 * v1;
    #pragma unroll
    for (int m = 1; m < 64; m <<= 1) {
        s  += __shfl_xor(s,  m, 64);
        ss += __shfl_xor(ss, m, 64);
    }
    float mu  = s * (1.f / 128.f);
    float var = ss * (1.f / 128.f) - mu * mu;
    float rs  = rsqrtf(var + 1e-12f);
    float n0 = (v0 - mu) * rs * g2a + b2a;
    float n1 = (v1 - mu) * rs * g2c + b2c;
    float dot = n0 * fwa + n1 * fwc;
    #pragma unroll
    for (int m = 1; m < 64; m <<= 1) dot += __shfl_xor(dot, m, 64);
    if (l == 0) out[r] = dot + fcb[0];
}

extern "C" void kernel_launch(void* const* d_in, const int* in_sizes, int n_in,
                              void* d_out, int out_size, void* d_ws, size_t ws_size,
                              hipStream_t stream) {
    const int*   ids  = (const int*)d_in[0];
    const int*   lens = (const int*)d_in[1];
    const float* emb  = (const float*)d_in[2];
    const float* ln1g = (const float*)d_in[3];
    const float* ln1b = (const float*)d_in[4];
    const float* w1   = (const float*)d_in[5];
    const float* b1   = (const float*)d_in[6];
    const float* w2   = (const float*)d_in[7];
    const float* b2   = (const float*)d_in[8];
    const float* ln2g = (const float*)d_in[9];
    const float* ln2b = (const float*)d_in[10];
    const float* fcw  = (const float*)d_in[11];
    const float* fcb  = (const float*)d_in[12];
    float* out = (float*)d_out;

    char* ws = (char*)d_ws;   // needs ~7.3 MB
    half8*    frags   = (half8*)(ws + WS_FRAGS);
    int*      cnt     = (int*)(ws + WS_CNT);
    unsigned* packed  = (unsigned*)(ws + WS_PACKED);
    float*    partial = (float*)(ws + WS_PARTIAL);

    hipLaunchKernelGGL(prep_kernel, dim3(4129), dim3(256), 0, stream,
                       w1, w2, frags, cnt, partial);
    hipLaunchKernelGGL(compact_kernel, dim3(16), dim3(256), 0, stream,
                       ids, lens, packed, cnt);
    hipLaunchKernelGGL(dense_kernel, dim3(DENSE_GRID), dim3(256), 0, stream,
                       packed, cnt, emb, ln1g, ln1b, b1, b2, frags, partial);
    hipLaunchKernelGGL(head_kernel, dim3(1024), dim3(256), 0, stream,
                       partial, ln2g, ln2b, fcw, fcb, out);
}

// Round 13
// 70.417 us; speedup vs baseline: 1.6574x; 1.6574x over previous
//
#include <hip/hip_runtime.h>
#include <hip/hip_bf16.h>
#include <math.h>

typedef __attribute__((ext_vector_type(8))) _Float16 half8;
typedef __attribute__((ext_vector_type(4))) _Float16 half4;
typedef __attribute__((ext_vector_type(4))) float f32x4;

#define EMBD 128
#define H1 256
#define H2 128
#define SLEN 50
#define NROWS 4096
#define MTILE 32
#define DENSE_GRID 256

// ---- d_ws layout (bytes) ----
#define WS_FRAGS   0          // half8 frags[8192]  (131072)
#define WS_CNT     131072     // int counter (pad to 131200)
#define WS_PACKED  131200     // u32 packed[204800] (819200) -> 950400
#define WS_PARTIAL 950400     // float partial[4096][3][128] (6291456) -> ~7.3MB

// Branch-free GELU, exact-erf form via Abramowitz-Stegun 7.1.26 (|err|<=1.5e-7).
__device__ __forceinline__ float gelu_exact(float h) {
    float ah = fabsf(h);
    float d  = fmaf(0.23163845f, ah, 1.0f);
    float t;
    asm("v_rcp_f32 %0, %1" : "=v"(t) : "v"(d));
    float p = fmaf(1.061405429f, t, -1.453152027f);
    p = fmaf(p, t, 1.421413741f);
    p = fmaf(p, t, -0.284496736f);
    p = fmaf(p, t, 0.254829592f);
    p = p * t;
    float e;                                   // v_exp_f32 computes 2^x
    float x2 = h * h * -0.72134752f;           // -h^2/2 * log2(e)
    asm("v_exp_f32 %0, %1" : "=v"(e) : "v"(x2));
    float er = fmaf(-p, e, 1.0f);
    return fmaf(0.5f * ah, er, 0.5f * h);
}

// LDS-only barrier (no vmcnt drain): in-flight global loads survive it.
#define BARRIER_LDS() asm volatile("s_waitcnt lgkmcnt(0)\n\ts_barrier" ::: "memory")

// ---------------------------------------------------------------------------
// K0: weight fragments for the LDS-resident layout + counter + partial init.
//   w1: fragid = kt*16+nt (kt<4, nt<16); entry f = fragid*64+lane
//       lane holds w1[kt*32 + (lane>>4)*8 + i][nt*16 + (lane&15)]
//   w2: fragid = kt*8+ntc (kt<8, ntc<8); entry 4096 + fragid*64+lane
// ---------------------------------------------------------------------------
__global__ __launch_bounds__(256) void prep_kernel(
    const float* __restrict__ w1, const float* __restrict__ w2,
    half8* __restrict__ frags, int* __restrict__ cnt,
    float* __restrict__ partial)
{
    int b = blockIdx.x, t = threadIdx.x;
    if (b < 32) {
        int f = b * 256 + t;   // 0..8191
        half8 v;
        if (f < 4096) {
            int fragid = f >> 6, lane = f & 63;
            int kt = fragid >> 4, nt = fragid & 15;
            int col = nt * 16 + (lane & 15);
            int kb  = kt * 32 + (lane >> 4) * 8;
            #pragma unroll
            for (int i = 0; i < 8; ++i) v[i] = (_Float16)w1[(size_t)(kb + i) * H1 + col];
            frags[f] = v;
        } else {
            int f2 = f - 4096;
            int fragid = f2 >> 6, lane = f2 & 63;
            int kt = fragid >> 3, ntc = fragid & 7;
            int col = ntc * 16 + (lane & 15);
            int kb  = kt * 32 + (lane >> 4) * 8;
            #pragma unroll
            for (int i = 0; i < 8; ++i) v[i] = (_Float16)w2[(size_t)(kb + i) * H2 + col];
            frags[4096 + f2] = v;
        }
    } else if (b == 32) {
        if (t == 0) *cnt = 0;
    } else {
        int idx = (b - 33) * 256 + t;
        if (idx < NROWS * 256) {
            int r = idx >> 8, rem = idx & 255;   // sides 1..2
            partial[(size_t)r * 384 + 128 + rem] = -INFINITY;
        }
    }
}

// ---------------------------------------------------------------------------
// K1: compact valid tokens -> packed[i] = emb_id | (row << 17). (R12, passed)
// ---------------------------------------------------------------------------
__global__ __launch_bounds__(256) void compact_kernel(
    const int* __restrict__ ids, const int* __restrict__ lens,
    unsigned* __restrict__ packed, int* __restrict__ cnt)
{
    int gtid = blockIdx.x * 256 + threadIdx.x;   // row 0..4095
    int lane = threadIdx.x & 63;
    int len = lens[gtid]; len = len < 1 ? 1 : (len > SLEN ? SLEN : len);
    int inc = len;
    #pragma unroll
    for (int off = 1; off < 64; off <<= 1) {
        int v = __shfl_up(inc, off, 64);
        if (lane >= off) inc += v;
    }
    int wave_total = __shfl(inc, 63, 64);
    int wbase;
    if (lane == 0) wbase = atomicAdd(cnt, wave_total);
    wbase = __shfl(wbase, 0, 64);
    int base = wbase + inc - len;
    unsigned rtag = (unsigned)gtid << 17;
    for (int t = 0; t < len; ++t)
        packed[base + t] = (unsigned)ids[gtid * SLEN + t] | rtag;
}

// ---------------------------------------------------------------------------
// K2: dense 32-token tiles, 512 threads (8 waves), weights streamed from LDS.
//   wave w: GEMM1 cols [w*32, w*32+32), GEMM2 cols [w*16, w*16+16)
//   LN1: 16-lane group g32 = w*4+lg owns token g32.
//   Pool: ballot segment mask; partial[row][side][col], side by tile parity.
// ---------------------------------------------------------------------------
__global__ __launch_bounds__(512) void dense_kernel(
    const unsigned* __restrict__ packed, const int* __restrict__ cnt,
    const float* __restrict__ emb, const float* __restrict__ ln1g,
    const float* __restrict__ ln1b, const float* __restrict__ b1,
    const float* __restrict__ b2, const half8* __restrict__ wfrag,
    float* __restrict__ partial)
{
    const int tid = threadIdx.x;
    const int w  = tid >> 6;    // wave 0..7
    const int l  = tid & 63;
    const int ln = l & 15;
    const int lg = l >> 4;
    const int g32 = w * 4 + lg; // token slot 0..31

    __shared__ __align__(16) half8 wlds[8192];                 // 128 KB
    __shared__ __align__(16) _Float16 x_lds[MTILE][EMBD + 8];  // 8.5 KB
    __shared__ __align__(16) _Float16 h1_lds[MTILE][H1 + 8];   // 16.5 KB
    __shared__ unsigned tok_lds[MTILE + 1];

    // ---- stage all weight fragments into LDS (once per block) ----
    #pragma unroll
    for (int i = 0; i < 16; ++i)
        wlds[i * 512 + tid] = wfrag[i * 512 + tid];

    float g1r[8], b1r[8];
    #pragma unroll
    for (int i = 0; i < 8; ++i) { g1r[i] = ln1g[ln * 8 + i]; b1r[i] = ln1b[ln * 8 + i]; }
    f32x4 b1tv[2];
    #pragma unroll
    for (int j = 0; j < 2; ++j)
        b1tv[j] = *(const f32x4*)&b1[(w * 2 + j) * 16 + lg * 4];
    const float b2s = b2[w * 16 + ln];

    const int total = *cnt;

    int tile = blockIdx.x;
    int base = tile * MTILE;

    // ---- prologue: prefetch tile0's pk/tok/emb ----
    unsigned pkA = 0xFFFFFFFFu, tokA = 0xFFFFFFFFu;
    float4 pa0, pa1; bool vA = false;
    if (base < total) {
        if (base + g32 < total) pkA = packed[base + g32];
        if (tid <= 32) {
            int ti = (tid < 32) ? base + tid : base - 1;
            tokA = (ti >= 0 && ti < total) ? packed[ti] : 0xFFFFFFFFu;
        }
        vA = (pkA != 0xFFFFFFFFu);
        if (vA) {
            int id = (int)(pkA & 0x1FFFFu);
            const float4* src = (const float4*)(emb + (size_t)id * EMBD + ln * 8);
            pa0 = src[0]; pa1 = src[1];
        }
    }

    for (; base < total; tile += (int)gridDim.x, base = tile * MTILE) {
        const int nbase = (tile + (int)gridDim.x) * MTILE;

        // stage this tile's row tags
        if (tid <= 32) tok_lds[tid] = tokA;

        // issue next tile's pk/tok loads (in flight across barriers)
        unsigned pkN = 0xFFFFFFFFu, tokN = 0xFFFFFFFFu;
        if (nbase < total) {
            if (nbase + g32 < total) pkN = packed[nbase + g32];
            if (tid <= 32) {
                int ti = (tid < 32) ? nbase + tid : nbase - 1;
                tokN = (ti < total) ? packed[ti] : 0xFFFFFFFFu;
            }
        }

        // ---- LN1 of own token -> x_lds ----
        {
            half8 xo;
            if (vA) {
                float v[8] = {pa0.x, pa0.y, pa0.z, pa0.w, pa1.x, pa1.y, pa1.z, pa1.w};
                float sm = 0.f, ss = 0.f;
                #pragma unroll
                for (int k = 0; k < 8; ++k) { sm += v[k]; ss += v[k] * v[k]; }
                #pragma unroll
                for (int m = 1; m < 16; m <<= 1) {
                    sm += __shfl_xor(sm, m, 64);
                    ss += __shfl_xor(ss, m, 64);
                }
                float mu  = sm * (1.f / 128.f);
                float var = ss * (1.f / 128.f) - mu * mu;
                float rs  = rsqrtf(var + 1e-12f);
                #pragma unroll
                for (int k = 0; k < 8; ++k)
                    xo[k] = (_Float16)((v[k] - mu) * rs * g1r[k] + b1r[k]);
            } else {
                #pragma unroll
                for (int k = 0; k < 8; ++k) xo[k] = (_Float16)0.f;
            }
            *(half8*)&x_lds[g32][ln * 8] = xo;
        }

        BARRIER_LDS();   // x_lds + tok_lds (+ wlds on first iter) ready

        // ---- GEMM1 (transposed): wave w -> H1 cols w*32..+31, frags from LDS ----
        f32x4 acc[2][2];
        acc[0][0] = (f32x4){0,0,0,0}; acc[0][1] = (f32x4){0,0,0,0};
        acc[1][0] = (f32x4){0,0,0,0}; acc[1][1] = (f32x4){0,0,0,0};
        #pragma unroll
        for (int kt = 0; kt < 4; ++kt) {
            half8 xf0 = *(const half8*)&x_lds[ln][kt * 32 + lg * 8];
            half8 xf1 = *(const half8*)&x_lds[16 + ln][kt * 32 + lg * 8];
            half8 wf0 = wlds[(kt * 16 + w * 2 + 0) * 64 + l];
            half8 wf1 = wlds[(kt * 16 + w * 2 + 1) * 64 + l];
            acc[0][0] = __builtin_amdgcn_mfma_f32_16x16x32_f16(wf0, xf0, acc[0][0], 0, 0, 0);
            acc[0][1] = __builtin_amdgcn_mfma_f32_16x16x32_f16(wf1, xf0, acc[0][1], 0, 0, 0);
            acc[1][0] = __builtin_amdgcn_mfma_f32_16x16x32_f16(wf0, xf1, acc[1][0], 0, 0, 0);
            acc[1][1] = __builtin_amdgcn_mfma_f32_16x16x32_f16(wf1, xf1, acc[1][1], 0, 0, 0);
        }

        // ---- issue next tile's emb gather (pkN has landed by now) ----
        float4 pb0, pb1; bool vN = (pkN != 0xFFFFFFFFu);
        if (vN) {
            int id = (int)(pkN & 0x1FFFFu);
            const float4* src = (const float4*)(emb + (size_t)id * EMBD + ln * 8);
            pb0 = src[0]; pb1 = src[1];
        }

        // ---- GELU -> h1_lds ----
        #pragma unroll
        for (int m = 0; m < 2; ++m)
          #pragma unroll
          for (int j = 0; j < 2; ++j) {
            half4 hv;
            #pragma unroll
            for (int g2 = 0; g2 < 4; ++g2) {
                float h = acc[m][j][g2] + b1tv[j][g2];
                hv[g2] = (_Float16)gelu_exact(h);
            }
            *(half4*)&h1_lds[m * 16 + ln][(w * 2 + j) * 16 + lg * 4] = hv;
          }

        // ---- read row tags into regs + ballot segment mask (before bar2) ----
        int rowj = 0x7FFF, rowp = 0x7FFF;
        if (l < 32) {
            rowj = (int)(tok_lds[l] >> 17);
            rowp = (l == 0) ? (int)(tok_lds[32] >> 17) : (int)(tok_lds[l - 1] >> 17);
        }
        const int prevrow = (int)(tok_lds[32] >> 17);
        bool st = (l < 32) && ((l == 0) || (rowj != rowp));
        unsigned mask = (unsigned)__ballot(st);   // bits 0..31 = segment starts

        BARRIER_LDS();   // h1_lds ready; tok_lds consumed

        // ---- GEMM2: wave w -> H2 cols w*16..+15 ----
        f32x4 acc2[2];
        acc2[0] = (f32x4){0,0,0,0}; acc2[1] = (f32x4){0,0,0,0};
        #pragma unroll
        for (int kt = 0; kt < 8; ++kt) {
            half8 a0 = *(const half8*)&h1_lds[ln][kt * 32 + lg * 8];
            half8 a1 = *(const half8*)&h1_lds[16 + ln][kt * 32 + lg * 8];
            half8 wf = wlds[4096 + (kt * 8 + w) * 64 + l];
            acc2[0] = __builtin_amdgcn_mfma_f32_16x16x32_f16(a0, wf, acc2[0], 0, 0, 0);
            acc2[1] = __builtin_amdgcn_mfma_f32_16x16x32_f16(a1, wf, acc2[1], 0, 0, 0);
        }
        float val[2][4];
        #pragma unroll
        for (int m = 0; m < 2; ++m)
          #pragma unroll
          for (int g2 = 0; g2 < 4; ++g2)
            val[m][g2] = acc2[m][g2] + b2s;

        // ---- segmented max-pool (scalar loop over ~2.3 segments) ----
        {
            int s0 = 0;
            while (s0 < 32) {
                int s1;
                if (s0 >= 31) s1 = 32;
                else {
                    unsigned m2 = mask >> (s0 + 1);
                    s1 = m2 ? (s0 + __ffs(m2)) : 32;
                }
                int row = __shfl(rowj, s0, 64);
                if (row < NROWS) {
                    float mx = -INFINITY;
                    #pragma unroll
                    for (int m = 0; m < 2; ++m)
                      #pragma unroll
                      for (int g2 = 0; g2 < 4; ++g2) {
                        int tt = m * 16 + lg * 4 + g2;
                        if (tt >= s0 && tt < s1) mx = fmaxf(mx, val[m][g2]);
                      }
                    mx = fmaxf(mx, __shfl_xor(mx, 16, 64));
                    mx = fmaxf(mx, __shfl_xor(mx, 32, 64));
                    int side = (s0 == 0 && row == prevrow) ? 1 + (tile & 1) : 0;
                    if (l < 16)
                        partial[(size_t)row * 384 + side * 128 + w * 16 + l] = mx;
                }
                s0 = s1;
            }
        }

        // ---- rotate prefetch state ----
        pkA = pkN; tokA = tokN; vA = vN;
        if (vN) { pa0 = pb0; pa1 = pb1; }
    }
}

// ---------------------------------------------------------------------------
// K3: pool = max over 3 sides -> LN2 -> fc. (R12, passed)
// ---------------------------------------------------------------------------
__global__ __launch_bounds__(256) void head_kernel(
    const float* __restrict__ partial, const float* __restrict__ ln2g,
    const float* __restrict__ ln2b, const float* __restrict__ fcw,
    const float* __restrict__ fcb, float* __restrict__ out)
{
    int w = threadIdx.x >> 6, l = threadIdx.x & 63;
    int r = blockIdx.x * 4 + w;
    const float* pr = partial + (size_t)r * 384;
    float v0 = fmaxf(fmaxf(pr[l],      pr[128 + l]),      pr[256 + l]);
    float v1 = fmaxf(fmaxf(pr[64 + l], pr[128 + 64 + l]), pr[256 + 64 + l]);
    float g2a = ln2g[l], g2c = ln2g[l + 64];
    float b2a = ln2b[l], b2c = ln2b[l + 64];
    float fwa = fcw[l],  fwc = fcw[l + 64];
    float s = v0 + v1, ss = v0 * v0 + v1 * v1;
    #pragma unroll
    for (int m = 1; m < 64; m <<= 1) {
        s  += __shfl_xor(s,  m, 64);
        ss += __shfl_xor(ss, m, 64);
    }
    float mu  = s * (1.f / 128.f);
    float var = ss * (1.f / 128.f) - mu * mu;
    float rs  = rsqrtf(var + 1e-12f);
    float n0 = (v0 - mu) * rs * g2a + b2a;
    float n1 = (v1 - mu) * rs * g2c + b2c;
    float dot = n0 * fwa + n1 * fwc;
    #pragma unroll
    for (int m = 1; m < 64; m <<= 1) dot += __shfl_xor(dot, m, 64);
    if (l == 0) out[r] = dot + fcb[0];
}

extern "C" void kernel_launch(void* const* d_in, const int* in_sizes, int n_in,
                              void* d_out, int out_size, void* d_ws, size_t ws_size,
                              hipStream_t stream) {
    const int*   ids  = (const int*)d_in[0];
    const int*   lens = (const int*)d_in[1];
    const float* emb  = (const float*)d_in[2];
    const float* ln1g = (const float*)d_in[3];
    const float* ln1b = (const float*)d_in[4];
    const float* w1   = (const float*)d_in[5];
    const float* b1   = (const float*)d_in[6];
    const float* w2   = (const float*)d_in[7];
    const float* b2   = (const float*)d_in[8];
    const float* ln2g = (const float*)d_in[9];
    const float* ln2b = (const float*)d_in[10];
    const float* fcw  = (const float*)d_in[11];
    const float* fcb  = (const float*)d_in[12];
    float* out = (float*)d_out;

    char* ws = (char*)d_ws;   // needs ~7.3 MB
    half8*    frags   = (half8*)(ws + WS_FRAGS);
    int*      cnt     = (int*)(ws + WS_CNT);
    unsigned* packed  = (unsigned*)(ws + WS_PACKED);
    float*    partial = (float*)(ws + WS_PARTIAL);

    hipLaunchKernelGGL(prep_kernel, dim3(4129), dim3(256), 0, stream,
                       w1, w2, frags, cnt, partial);
    hipLaunchKernelGGL(compact_kernel, dim3(16), dim3(256), 0, stream,
                       ids, lens, packed, cnt);
    hipLaunchKernelGGL(dense_kernel, dim3(DENSE_GRID), dim3(512), 0, stream,
                       packed, cnt, emb, ln1g, ln1b, b1, b2, frags, partial);
    hipLaunchKernelGGL(head_kernel, dim3(1024), dim3(256), 0, stream,
                       partial, ln2g, ln2b, fcw, fcb, out);
}